// Round 1
// baseline (1642.489 us; speedup 1.0000x reference)
//
#include <hip/hip_runtime.h>
#include <math.h>

#define N_FRAMES 512
#define TOKENS   196
#define EMBED    2560
#define HIDDEN   512
#define E4       (EMBED / 4)   // 640

// ---------------- block reduction helper ----------------
__device__ __forceinline__ float block_reduce_sum(float v, float* smem, int tid, int nthreads) {
    __syncthreads();                       // protect smem reuse across calls
    #pragma unroll
    for (int off = 32; off > 0; off >>= 1) v += __shfl_down(v, off);
    int wid = tid >> 6;
    if ((tid & 63) == 0) smem[wid] = v;
    __syncthreads();
    if (tid == 0) {
        float s = smem[0];
        int nw = nthreads >> 6;
        for (int w = 1; w < nw; ++w) s += smem[w];
        smem[0] = s;
    }
    __syncthreads();
    return smem[0];
}

// ---------------- kernel 1: pooled mean + layernorm + norm ----------------
// one block per frame; 640 threads, each owns one float4 column group.
__global__ __launch_bounds__(640) void pool_ln_kernel(
    const float* __restrict__ img, const float* __restrict__ g,
    const float* __restrict__ b, float* __restrict__ out_ln,
    float* __restrict__ norms)
{
    int n = blockIdx.x;
    int tid = threadIdx.x;
    __shared__ float red[16];

    const float4* src = (const float4*)(img + (size_t)n * TOKENS * EMBED);
    float4 acc = make_float4(0.f, 0.f, 0.f, 0.f);
    #pragma unroll 4
    for (int t = 0; t < TOKENS; ++t) {
        float4 v = src[t * E4 + tid];
        acc.x += v.x; acc.y += v.y; acc.z += v.z; acc.w += v.w;
    }
    const float invT = 1.0f / (float)TOKENS;
    acc.x *= invT; acc.y *= invT; acc.z *= invT; acc.w *= invT;

    float s1 = acc.x + acc.y + acc.z + acc.w;
    float s2 = acc.x*acc.x + acc.y*acc.y + acc.z*acc.z + acc.w*acc.w;
    s1 = block_reduce_sum(s1, red, tid, 640);
    s2 = block_reduce_sum(s2, red, tid, 640);

    float mean = s1 * (1.0f / EMBED);
    float var  = s2 * (1.0f / EMBED) - mean * mean;
    float inv  = 1.0f / sqrtf(var + 1e-5f);

    float4 gg = ((const float4*)g)[tid];
    float4 bb = ((const float4*)b)[tid];
    float4 o;
    o.x = (acc.x - mean) * inv * gg.x + bb.x;
    o.y = (acc.y - mean) * inv * gg.y + bb.y;
    o.z = (acc.z - mean) * inv * gg.z + bb.z;
    o.w = (acc.w - mean) * inv * gg.w + bb.w;
    ((float4*)(out_ln + (size_t)n * EMBED))[tid] = o;

    float ss = o.x*o.x + o.y*o.y + o.z*o.z + o.w*o.w;
    ss = block_reduce_sum(ss, red, tid, 640);
    if (tid == 0) norms[n] = fmaxf(sqrtf(ss), 1e-8f);
}

// ---------------- kernel 2a: text layernorm + inits ----------------
__global__ __launch_bounds__(640) void txt_ln_kernel(
    const float* __restrict__ txt, const float* __restrict__ g,
    const float* __restrict__ b, const float* __restrict__ b1,
    const float* __restrict__ b2, float* __restrict__ txt_ln,
    float* __restrict__ txt_c, float* __restrict__ logits)
{
    int tid = threadIdx.x;
    __shared__ float red[16];
    float4 v = ((const float4*)txt)[tid];
    float s1 = v.x + v.y + v.z + v.w;
    float s2 = v.x*v.x + v.y*v.y + v.z*v.z + v.w*v.w;
    s1 = block_reduce_sum(s1, red, tid, 640);
    s2 = block_reduce_sum(s2, red, tid, 640);
    float mean = s1 * (1.0f / EMBED);
    float var  = s2 * (1.0f / EMBED) - mean * mean;
    float inv  = 1.0f / sqrtf(var + 1e-5f);
    float4 gg = ((const float4*)g)[tid];
    float4 bb = ((const float4*)b)[tid];
    float4 o;
    o.x = (v.x - mean) * inv * gg.x + bb.x;
    o.y = (v.y - mean) * inv * gg.y + bb.y;
    o.z = (v.z - mean) * inv * gg.z + bb.z;
    o.w = (v.w - mean) * inv * gg.w + bb.w;
    ((float4*)txt_ln)[tid] = o;
    if (tid < HIDDEN) {
        txt_c[tid]  = b1[tid];
        logits[tid] = b2[0];
    }
}

// ---------------- kernel 2b: txt_c += txt_ln @ W1[:2560,:] (K-split) ----------------
__global__ __launch_bounds__(512) void txt_proj_kernel(
    const float* __restrict__ txt_ln, const float* __restrict__ W1,
    float* __restrict__ txt_c)
{
    __shared__ float t[128];
    int tid = threadIdx.x;
    int k0 = blockIdx.x * 128;
    if (tid < 128) t[tid] = txt_ln[k0 + tid];
    __syncthreads();
    float s = 0.f;
    const float* w = W1 + (size_t)k0 * HIDDEN + tid;
    #pragma unroll 8
    for (int k = 0; k < 128; ++k) s += t[k] * w[(size_t)k * HIDDEN];
    atomicAdd(&txt_c[tid], s);
}

// ---------------- kernel 3: H = relu(A @ W1_low + txt_c); logits += H @ W2 ----------------
#define BM 64
#define BN 64
#define BK 16

__global__ __launch_bounds__(256) void hidden_logit_kernel(
    const float* __restrict__ A, const float* __restrict__ W1,
    const float* __restrict__ txt_c, const float* __restrict__ W2,
    float* __restrict__ logits)
{
    const float* Bm = W1 + (size_t)EMBED * HIDDEN;  // pooled half
    __shared__ float As[BK][BM + 4];
    __shared__ float Bs[BK][BN];
    int tid = threadIdx.x;
    int row0 = blockIdx.y * BM, col0 = blockIdx.x * BN;
    int tm = tid >> 4, tn = tid & 15;
    int a_row = tid >> 2, a_k = (tid & 3) * 4;
    int b_k = tid >> 4, b_j = (tid & 15) * 4;
    float acc[4][4] = {};

    for (int k0 = 0; k0 < EMBED; k0 += BK) {
        float4 av = *(const float4*)(A  + (size_t)(row0 + a_row) * EMBED  + k0 + a_k);
        float4 bv = *(const float4*)(Bm + (size_t)(k0 + b_k)    * HIDDEN + col0 + b_j);
        __syncthreads();
        As[a_k + 0][a_row] = av.x;
        As[a_k + 1][a_row] = av.y;
        As[a_k + 2][a_row] = av.z;
        As[a_k + 3][a_row] = av.w;
        *(float4*)&Bs[b_k][b_j] = bv;
        __syncthreads();
        #pragma unroll
        for (int k = 0; k < BK; ++k) {
            float4 a = *(const float4*)&As[k][tm * 4];
            float4 b = *(const float4*)&Bs[k][tn * 4];
            acc[0][0] += a.x*b.x; acc[0][1] += a.x*b.y; acc[0][2] += a.x*b.z; acc[0][3] += a.x*b.w;
            acc[1][0] += a.y*b.x; acc[1][1] += a.y*b.y; acc[1][2] += a.y*b.z; acc[1][3] += a.y*b.w;
            acc[2][0] += a.z*b.x; acc[2][1] += a.z*b.y; acc[2][2] += a.z*b.z; acc[2][3] += a.z*b.w;
            acc[3][0] += a.w*b.x; acc[3][1] += a.w*b.y; acc[3][2] += a.w*b.z; acc[3][3] += a.w*b.w;
        }
    }

    int col = col0 + tn * 4;
    float tc0 = txt_c[col + 0], tc1 = txt_c[col + 1], tc2 = txt_c[col + 2], tc3 = txt_c[col + 3];
    float w0 = W2[col + 0], w1 = W2[col + 1], w2 = W2[col + 2], w3 = W2[col + 3];
    float p[4];
    #pragma unroll
    for (int i = 0; i < 4; ++i) {
        float h0 = fmaxf(acc[i][0] + tc0, 0.f);
        float h1 = fmaxf(acc[i][1] + tc1, 0.f);
        float h2 = fmaxf(acc[i][2] + tc2, 0.f);
        float h3 = fmaxf(acc[i][3] + tc3, 0.f);
        p[i] = h0 * w0 + h1 * w1 + h2 * w2 + h3 * w3;
    }
    #pragma unroll
    for (int i = 0; i < 4; ++i) {
        #pragma unroll
        for (int off = 8; off > 0; off >>= 1) p[i] += __shfl_down(p[i], off, 16);
    }
    if (tn == 0) {
        int row = row0 + tm * 4;
        #pragma unroll
        for (int i = 0; i < 4; ++i) atomicAdd(&logits[row + i], p[i]);
    }
}

// ---------------- kernel 4: gram G = A @ A^T ----------------
__global__ __launch_bounds__(256) void gram_kernel(
    const float* __restrict__ A, float* __restrict__ G)
{
    __shared__ float As[BK][BM + 4];
    __shared__ float Bs[BK][BN + 4];
    int tid = threadIdx.x;
    int row0 = blockIdx.y * BM, col0 = blockIdx.x * BN;
    int tm = tid >> 4, tn = tid & 15;
    int l_row = tid >> 2, l_k = (tid & 3) * 4;
    float acc[4][4] = {};

    for (int k0 = 0; k0 < EMBED; k0 += BK) {
        float4 av = *(const float4*)(A + (size_t)(row0 + l_row) * EMBED + k0 + l_k);
        float4 bv = *(const float4*)(A + (size_t)(col0 + l_row) * EMBED + k0 + l_k);
        __syncthreads();
        As[l_k + 0][l_row] = av.x;
        As[l_k + 1][l_row] = av.y;
        As[l_k + 2][l_row] = av.z;
        As[l_k + 3][l_row] = av.w;
        Bs[l_k + 0][l_row] = bv.x;
        Bs[l_k + 1][l_row] = bv.y;
        Bs[l_k + 2][l_row] = bv.z;
        Bs[l_k + 3][l_row] = bv.w;
        __syncthreads();
        #pragma unroll
        for (int k = 0; k < BK; ++k) {
            float4 a = *(const float4*)&As[k][tm * 4];
            float4 b = *(const float4*)&Bs[k][tn * 4];
            acc[0][0] += a.x*b.x; acc[0][1] += a.x*b.y; acc[0][2] += a.x*b.z; acc[0][3] += a.x*b.w;
            acc[1][0] += a.y*b.x; acc[1][1] += a.y*b.y; acc[1][2] += a.y*b.z; acc[1][3] += a.y*b.w;
            acc[2][0] += a.z*b.x; acc[2][1] += a.z*b.y; acc[2][2] += a.z*b.z; acc[2][3] += a.z*b.w;
            acc[3][0] += a.w*b.x; acc[3][1] += a.w*b.y; acc[3][2] += a.w*b.z; acc[3][3] += a.w*b.w;
        }
    }
    #pragma unroll
    for (int i = 0; i < 4; ++i) {
        float4 o = make_float4(acc[i][0], acc[i][1], acc[i][2], acc[i][3]);
        *(float4*)&G[(size_t)(row0 + tm * 4 + i) * N_FRAMES + col0 + tn * 4] = o;
    }
}

// ---------------- kernel 5: gates + sort + greedy selection ----------------
__global__ __launch_bounds__(512) void select_kernel(
    const float* __restrict__ logits, const float* __restrict__ norms,
    const float* __restrict__ G, float* __restrict__ out)
{
    int tid = threadIdx.x;
    __shared__ float s_g[N_FRAMES];
    __shared__ float s_n[N_FRAMES];
    __shared__ int   s_order[N_FRAMES];
    __shared__ unsigned char s_vis[N_FRAMES];
    __shared__ unsigned char s_sel[N_FRAMES];

    float gate = 1.0f / (1.0f + expf(-logits[tid]));
    s_g[tid] = gate;
    s_n[tid] = norms[tid];
    s_vis[tid] = 0;
    s_sel[tid] = 0;
    out[N_FRAMES + tid] = gate;   // gates output
    __syncthreads();

    // stable descending rank (matches argsort(-gates), stable)
    int r = 0;
    float g = s_g[tid];
    for (int j = 0; j < N_FRAMES; ++j) {
        float gj = s_g[j];
        r += (gj > g) || (gj == g && j < tid);
    }
    s_order[r] = tid;
    __syncthreads();

    int count = 0;
    float my_n = s_n[tid];
    for (int it = 0; it < N_FRAMES; ++it) {
        int cur = s_order[it];
        int take = (s_vis[cur] == 0);   // count<32 handled by break; score>=-1 always true
        __syncthreads();                // everyone has read s_vis[cur]
        if (take) {
            float thr = 0.98f * s_n[cur] * my_n;
            if (G[(size_t)cur * N_FRAMES + tid] > thr) s_vis[tid] = 1;
            if (tid == cur) { s_vis[tid] = 1; s_sel[tid] = 1; }
            ++count;                    // uniform across threads
            if (count >= 32) break;     // uniform break
        }
        __syncthreads();
    }
    __syncthreads();
    out[tid] = (float)s_sel[tid];       // selected output
}

// ---------------- host launcher ----------------
extern "C" void kernel_launch(void* const* d_in, const int* in_sizes, int n_in,
                              void* d_out, int out_size, void* d_ws, size_t ws_size,
                              hipStream_t stream) {
    const float* img    = (const float*)d_in[0];
    const float* txt    = (const float*)d_in[1];
    const float* ln_t_g = (const float*)d_in[2];
    const float* ln_t_b = (const float*)d_in[3];
    const float* ln_l_g = (const float*)d_in[4];
    const float* ln_l_b = (const float*)d_in[5];
    const float* W1     = (const float*)d_in[6];
    const float* b1     = (const float*)d_in[7];
    const float* W2     = (const float*)d_in[8];
    const float* b2     = (const float*)d_in[9];
    float* out = (float*)d_out;
    float* ws  = (float*)d_ws;

    // ws layout (floats): total ~6.3 MB
    float* pooled_ln = ws;                        // 512*2560
    float* G         = pooled_ln + N_FRAMES * EMBED;   // 512*512
    float* txt_ln    = G + N_FRAMES * N_FRAMES;   // 2560
    float* txt_c     = txt_ln + EMBED;            // 512
    float* logits    = txt_c + HIDDEN;            // 512
    float* norms     = logits + N_FRAMES;         // 512

    pool_ln_kernel<<<N_FRAMES, 640, 0, stream>>>(img, ln_l_g, ln_l_b, pooled_ln, norms);
    txt_ln_kernel<<<1, 640, 0, stream>>>(txt, ln_t_g, ln_t_b, b1, b2, txt_ln, txt_c, logits);
    txt_proj_kernel<<<EMBED / 128, 512, 0, stream>>>(txt_ln, W1, txt_c);
    hidden_logit_kernel<<<dim3(HIDDEN / BN, N_FRAMES / BM), 256, 0, stream>>>(
        pooled_ln, W1, txt_c, W2, logits);
    gram_kernel<<<dim3(N_FRAMES / BN, N_FRAMES / BM), 256, 0, stream>>>(pooled_ln, G);
    select_kernel<<<1, 512, 0, stream>>>(logits, norms, G, out);
}